// Round 13
// baseline (71.884 us; speedup 1.0000x reference)
//
#include <hip/hip_runtime.h>
#include <hip/hip_fp16.h>

typedef _Float16 half8  __attribute__((ext_vector_type(8)));
typedef _Float16 half4  __attribute__((ext_vector_type(4)));
typedef _Float16 h2v    __attribute__((ext_vector_type(2)));
typedef __fp16   fp16x2 __attribute__((ext_vector_type(2)));
typedef float    f32x4  __attribute__((ext_vector_type(4)));

#define B_N    2048
#define KLTOT  2048
#define NBLK   512        // grid size == co-resident capacity (2 blocks/CU x 256 CU)
#define XCS    580        // xt col stride (dwords): %32==4, %4==0
#define LJS2   36         // xt lj stride: %32==4, %4==0

// 5/5/4/4 h-slot packing
__device__ __forceinline__ int hmap(int g, int e) {
    return (g < 2) ? ((e < 5) ? g * 5 + e : -1)
                   : ((e < 4) ? 10 + (g - 2) * 4 + e : -1);
}

__device__ __forceinline__ unsigned int f16b(float f) {
    union { _Float16 h; unsigned short u; } c;
    c.h = (_Float16)f;
    return (unsigned int)c.u;
}

// Single worker kernel: stats + prep + MLP with manual grid handshake.
// 512 blocks x 512 thr, 2/CU (all co-resident). Block = 16 cols x 512 rows.
__global__ __launch_bounds__(512, 4) void fused_all(
    const float* __restrict__ x,
    const float* __restrict__ W1, const float* __restrict__ b1,
    const float* __restrict__ W2, const float* __restrict__ b2,
    const float* __restrict__ W3, const float* __restrict__ b3,
    float* __restrict__ part, unsigned int* __restrict__ cnt,
    float* __restrict__ out)
{
    __shared__ float        xt[16 * XCS];        // 37.1 KB  [col][(r&15)*36 + (r>>4)]
    __shared__ unsigned int afb[16 * 256];       // 16 KB    W2tmp then A-frags
    __shared__ float        red[512][2];         // 4 KB
    __shared__ unsigned int w1h[16][16], b1h[16][16], w3h[16][8];
    __shared__ float        b2f[16][16], smu[16], srs[16], sb3v[16];

    const int tid = threadIdx.x;
    const int bid = blockIdx.x;
    const int cgp = bid & 127, rg = bid >> 7;
    const int cols0 = cgp * 16, rows0 = rg * 512;

    // ---- S1: stage x tile once: LDS + per-thread stats ----
    {
        const int c = tid & 15, rr = tid >> 4;     // rr: 16-row group (0..31)
        float s = 0.f, s2 = 0.f;
#pragma unroll
        for (int i = 0; i < 16; ++i) {
            int r = rr * 16 + i;
            float v = x[(size_t)(rows0 + r) * KLTOT + cols0 + c];
            s += v; s2 = fmaf(v, v, s2);
            xt[c * XCS + i * LJS2 + rr] = v;
        }
        red[tid][0] = s; red[tid][1] = s2;
    }
    __syncthreads();

    // ---- S2: column partial sums -> global, release-publish ----
    if (tid < 16) {
        float S = 0.f, S2 = 0.f;
#pragma unroll 8
        for (int m = 0; m < 32; ++m) {
            S  += red[tid + 16 * m][0];
            S2 += red[tid + 16 * m][1];
        }
        float2 o = { S, S2 };
        *(float2*)&part[((size_t)rg * KLTOT + cols0 + tid) * 2] = o;
        __threadfence();                           // device-scope: flush to coherence point
    }
    __syncthreads();
    if (tid == 0)
        __hip_atomic_fetch_add(cnt, 1u, __ATOMIC_RELEASE, __HIP_MEMORY_SCOPE_AGENT);

    // ---- S3 (mu-independent prep, overlaps other blocks' stats) ----
    {
        float* W2tmp = (float*)afb;
        const float4* src = (const float4*)(W2 + (size_t)cols0 * 216);
        for (int i = tid; i < 864; i += 512)
            ((float4*)W2tmp)[i] = src[i];
    }
    // prefetch raw W1/b1 (folded after stats arrive); W3/b2/b3 tables now
    float w1r0 = 0.f, w1r1 = 0.f, b1r0 = 0.f, b1r1 = 0.f;
    if (tid < 256) {
        int c2 = tid >> 4, l = tid & 15;
        int gg = l >> 2, q = l & 3;
        if (q < 3) {
            int h0 = hmap(gg, q * 2), h1_ = hmap(gg, q * 2 + 1);
            if (h0 >= 0) {
                w1r0 = W1[(size_t)(cols0 + c2) * 18 + h0];
                b1r0 = b1[(size_t)(cols0 + c2) * 18 + h0];
            }
            if (h1_ >= 0) {
                w1r1 = W1[(size_t)(cols0 + c2) * 18 + h1_];
                b1r1 = b1[(size_t)(cols0 + c2) * 18 + h1_];
            }
        }
        b2f[c2][l] = (l < 12) ? b2[(size_t)(cols0 + c2) * 12 + l] : 0.f;
    } else if (tid < 384) {
        int t2 = tid - 256;
        int c2 = t2 >> 3, l = t2 & 7;
        int j0 = 2 * l, j1 = 2 * l + 1;
        float v0 = (j0 < 12) ? W3[(size_t)(cols0 + c2) * 12 + j0] : 0.f;
        float v1 = (j1 < 12) ? W3[(size_t)(cols0 + c2) * 12 + j1] : 0.f;
        w3h[c2][l] = f16b(v0) | (f16b(v1) << 16);
    } else if (tid < 400) {
        sb3v[tid - 384] = b3[cols0 + tid - 384];
    }
    __syncthreads();

    // pack A-frags from W2tmp into regs, then overwrite afb
    unsigned int dw[8];
    {
        const float* W2tmp = (const float*)afb;
        const int col = tid >> 5, d0 = (tid & 31) * 8;
#pragma unroll
        for (int k = 0; k < 8; ++k) {
            int d = d0 + k;
            unsigned int u[2];
#pragma unroll
            for (int h = 0; h < 2; ++h) {
                int idx = d * 2 + h;
                int gg = idx >> 7, j = (idx >> 3) & 15, e = idx & 7;
                int hh = hmap(gg, e);
                float v = (hh >= 0 && j < 12) ? W2tmp[col * 216 + hh * 12 + j] : 0.f;
                u[h] = f16b(v);
            }
            dw[k] = u[0] | (u[1] << 16);
        }
    }
    __syncthreads();
    {
        const int col = tid >> 5, d0 = (tid & 31) * 8;
#pragma unroll
        for (int k = 0; k < 8; ++k)
            afb[col * 256 + d0 + k] = dw[k];
    }

    // ---- grid handshake: leader spin (bounded), then per-reader acquire ----
    if (tid == 0) {
        long it = 0;
        while (__hip_atomic_load(cnt, __ATOMIC_ACQUIRE, __HIP_MEMORY_SCOPE_AGENT) < NBLK
               && ++it < (1L << 30)) { }
    }
    __syncthreads();

    if (tid < 16) {
        (void)__hip_atomic_load(cnt, __ATOMIC_ACQUIRE, __HIP_MEMORY_SCOPE_AGENT);
        float S = 0.f, S2 = 0.f;
#pragma unroll
        for (int q = 0; q < 4; ++q) {
            float2 v = *(const float2*)&part[((size_t)q * KLTOT + cols0 + tid) * 2];
            S += v.x; S2 += v.y;
        }
        float mu  = S / (float)B_N;
        float var = fmaxf(S2 / (float)B_N - mu * mu, 0.f);
        smu[tid] = mu;
        srs[tid] = 1.f / (sqrtf(var) + 1e-8f);
    }
    __syncthreads();

    // fold standardization into prefetched W1/b1
    if (tid < 256) {
        int c2 = tid >> 4, l = tid & 15;
        int q = l & 3;
        unsigned int wu = 0, bu = 0;
        if (q < 3) {
            float mu = smu[c2], rs = srs[c2];
            float w0 = w1r0 * rs, w1v = w1r1 * rs;
            float b0 = fmaf(-mu, w0, b1r0), b1v = fmaf(-mu, w1v, b1r1);
            wu = f16b(w0) | (f16b(w1v) << 16);
            bu = f16b(b0) | (f16b(b1v) << 16);
        }
        w1h[c2][l] = wu;
        b1h[c2][l] = bu;
    }
    __syncthreads();

    // ---- Phase C: dual chained MFMA (R12-proven), 2 cols/wave, 32 rb/col ----
    const int w = tid >> 6, l = tid & 63;
    const int g = l >> 4, lj = l & 15;
    const h2v z2 = {(_Float16)0.f, (_Float16)0.f};
    const f32x4 zc = {0.f, 0.f, 0.f, 0.f};

#pragma unroll
    for (int half = 0; half < 2; ++half) {
        const int cl = w + half * 8;

        union { uint4 u; half8 h; } af;
        af.u = *(const uint4*)&afb[cl * 256 + (g * 16 + lj) * 4];
        union { uint4 u; h2v p[4]; } w1u, b1u;
        w1u.u = *(const uint4*)&w1h[cl][g * 4];
        b1u.u = *(const uint4*)&b1h[cl][g * 4];
        union { uint2 u; half4 h; } a2;
        a2.u = *(const uint2*)&w3h[cl][g * 2];
        f32x4 b2r = *(const f32x4*)&b2f[cl][g * 4];
        float b3v = sb3v[cl];

        float res[8];
        const float* xb = &xt[cl * XCS + lj * LJS2];
#pragma unroll
        for (int rbq = 0; rbq < 4; ++rbq) {
            f32x4 xa = *(const f32x4*)(xb + rbq * 8);
            f32x4 xc = *(const f32x4*)(xb + rbq * 8 + 4);
#pragma unroll
            for (int k = 0; k < 8; ++k) {
                float xsv = (k < 4) ? xa[k & 3] : xc[k & 3];
                _Float16 xh = (_Float16)xsv;
                h2v x2 = {xh, xh};
                union { h2v p[4]; half8 h; } bf;
                bf.p[0] = __builtin_elementwise_max(x2 * w1u.p[0] + b1u.p[0], z2);
                bf.p[1] = __builtin_elementwise_max(x2 * w1u.p[1] + b1u.p[1], z2);
                bf.p[2] = __builtin_elementwise_max(x2 * w1u.p[2] + b1u.p[2], z2);
                bf.p[3] = z2;

                f32x4 acc = __builtin_amdgcn_mfma_f32_16x16x32_f16(af.h, bf.h, b2r, 0, 0, 0);

                union { fp16x2 c[2]; half4 h; } zf;
                zf.c[0] = __builtin_amdgcn_cvt_pkrtz(fmaxf(acc[0], 0.f), fmaxf(acc[1], 0.f));
                zf.c[1] = __builtin_amdgcn_cvt_pkrtz(fmaxf(acc[2], 0.f), fmaxf(acc[3], 0.f));

                f32x4 acc2 = __builtin_amdgcn_mfma_f32_16x16x16f16(a2.h, zf.h, zc, 0, 0, 0);

                if (rbq == g) res[k] = acc2[0] + b3v;
            }
        }
        float* tb = &xt[cl * XCS + lj * LJS2 + g * 8];
        f32x4 r0 = { res[0], res[1], res[2], res[3] };
        f32x4 r1 = { res[4], res[5], res[6], res[7] };
        *(f32x4*)tb = r0;
        *(f32x4*)(tb + 4) = r1;
    }
    __syncthreads();

    // ---- store: out[r][c] from xt ----
#pragma unroll
    for (int p = 0; p < 4; ++p) {
        int idx = p * 512 + tid;
        int c4 = idx & 3, r = idx >> 2;
        int base = (r & 15) * LJS2 + (r >> 4);
        f32x4 v;
#pragma unroll
        for (int e = 0; e < 4; ++e)
            v[e] = xt[(c4 * 4 + e) * XCS + base];
        *(f32x4*)(out + (size_t)(rows0 + r) * KLTOT + cols0 + c4 * 4) = v;
    }
}

extern "C" void kernel_launch(void* const* d_in, const int* in_sizes, int n_in,
                              void* d_out, int out_size, void* d_ws, size_t ws_size,
                              hipStream_t stream) {
    const float* x  = (const float*)d_in[0];
    const float* W1 = (const float*)d_in[1];
    const float* b1 = (const float*)d_in[2];
    const float* W2 = (const float*)d_in[3];
    const float* b2 = (const float*)d_in[4];
    const float* W3 = (const float*)d_in[5];
    const float* b3 = (const float*)d_in[6];
    float* out = (float*)d_out;

    float*        part = (float*)d_ws;                   // 4*2048*2 floats = 64 KB
    unsigned int* cnt  = (unsigned int*)((char*)d_ws + 4 * 2048 * 2 * sizeof(float));

    hipMemsetAsync(cnt, 0, sizeof(unsigned int), stream);   // deterministic handshake reset
    fused_all<<<dim3(NBLK), 512, 0, stream>>>(x, W1, b1, W2, b2, W3, b3,
                                              part, cnt, out);
}

// Round 14
// 34.851 us; speedup vs baseline: 2.0626x; 2.0626x over previous
//
#include <hip/hip_runtime.h>
#include <hip/hip_fp16.h>

typedef _Float16 half8  __attribute__((ext_vector_type(8)));
typedef _Float16 half4  __attribute__((ext_vector_type(4)));
typedef _Float16 h2v    __attribute__((ext_vector_type(2)));
typedef __fp16   fp16x2 __attribute__((ext_vector_type(2)));
typedef float    f32x4  __attribute__((ext_vector_type(4)));

#define B_N    2048
#define KLTOT  2048
#define NCHUNK 128
#define CHUNK_ROWS 16     // B_N / NCHUNK
#define CS2    258        // xt col stride (dwords)

// 5/5/4/4 h-slot packing
__device__ __forceinline__ int hmap(int g, int e) {
    return (g < 2) ? ((e < 5) ? g * 5 + e : -1)
                   : ((e < 4) ? 10 + (g - 2) * 4 + e : -1);
}

__device__ __forceinline__ unsigned int f16b(float f) {
    union { _Float16 h; unsigned short u; } c;
    c.h = (_Float16)f;
    return (unsigned int)c.u;
}

// ---------------- kernel 1: stats partials (proven) ----------------
__global__ __launch_bounds__(256) void stats_partial(const float* __restrict__ x,
                                                     float* __restrict__ part) {
    int c4 = blockIdx.x * 256 + threadIdx.x;          // 0..511
    int chunk = blockIdx.y;                           // 0..127
    const float4* p = (const float4*)(x + (size_t)(chunk * CHUNK_ROWS) * KLTOT) + c4;
    float4 s = {0.f, 0.f, 0.f, 0.f}, s2 = {0.f, 0.f, 0.f, 0.f};
#pragma unroll
    for (int r = 0; r < CHUNK_ROWS; ++r) {
        float4 v = p[(size_t)r * (KLTOT / 4)];
        s.x += v.x; s.y += v.y; s.z += v.z; s.w += v.w;
        s2.x = fmaf(v.x, v.x, s2.x); s2.y = fmaf(v.y, v.y, s2.y);
        s2.z = fmaf(v.z, v.z, s2.z); s2.w = fmaf(v.w, v.w, s2.w);
    }
    float4* o = (float4*)(part + ((size_t)chunk * KLTOT + (size_t)c4 * 4) * 2);
    float4 o0 = {s.x, s2.x, s.y, s2.y};
    float4 o1 = {s.z, s2.z, s.w, s2.w};
    o[0] = o0;
    o[1] = o1;
}

// ---------------- kernel 2: fused finalize + prep + MLP ----------------
// 1024 blocks x 512 thr, 4/CU (one generation). Block = 16 cols x 256 rows.
__global__ __launch_bounds__(512, 8) void fused_main(
    const float* __restrict__ x,
    const float* __restrict__ part,
    const float* __restrict__ W1, const float* __restrict__ b1,
    const float* __restrict__ W2, const float* __restrict__ b2,
    const float* __restrict__ W3, const float* __restrict__ b3,
    float* __restrict__ out)
{
    __shared__ float        xt[16 * CS2];        // 16.5 KB  [col][row]
    __shared__ unsigned int afb[16 * 256];       // 16 KB    W2tmp then A-frags
    __shared__ float        red[512][2];         // 4 KB
    __shared__ unsigned int w1h[16][16], b1h[16][16], w3h[16][8];
    __shared__ float        b2f[16][16], smu[16], srs[16], sb3v[16];

    const int tid = threadIdx.x;
    // XCD-chunked swizzle (1024 blocks, 8 XCDs, 128/chunk; bijective)
    const int bid = blockIdx.x;
    const int nf  = (bid & 7) * 128 + (bid >> 3);
    const int cgp = nf & 127, rg = nf >> 7;
    const int cols0 = cgp * 16, rows0 = rg * 256;

    // ---- S1: finalize stats partials (L2-hit) + stage x tile ----
    {
        const int c = tid & 15, q = tid >> 4;      // q: 0..31
        float s = 0.f, s2 = 0.f;
#pragma unroll
        for (int m = 0; m < 4; ++m) {
            float2 v = *(const float2*)&part[((size_t)(q + 32 * m) * KLTOT + cols0 + c) * 2];
            s += v.x; s2 += v.y;
        }
        red[tid][0] = s; red[tid][1] = s2;
    }
    {
        const int c = tid & 15, rr = tid >> 4;     // rr: 8-row group (0..31)
#pragma unroll
        for (int i = 0; i < 8; ++i) {
            int r = rr * 8 + i;
            xt[c * CS2 + r] = x[(size_t)(rows0 + r) * KLTOT + cols0 + c];
        }
    }
    __syncthreads();

    // ---- S2: finish stats; stage W2 into afb ----
    if (tid < 16) {
        float S = 0.f, S2 = 0.f;
#pragma unroll 8
        for (int m = 0; m < 32; ++m) {
            S  += red[tid + 16 * m][0];
            S2 += red[tid + 16 * m][1];
        }
        float mu  = S / (float)B_N;
        float var = fmaxf(S2 / (float)B_N - mu * mu, 0.f);
        smu[tid]  = mu;
        srs[tid]  = 1.f / (sqrtf(var) + 1e-8f);
        sb3v[tid] = b3[cols0 + tid];
    }
    {
        float* W2tmp = (float*)afb;
        const float4* src = (const float4*)(W2 + (size_t)cols0 * 216);
        for (int i = tid; i < 864; i += 512)
            ((float4*)W2tmp)[i] = src[i];
    }
    __syncthreads();

    // ---- S3: frag-pack W2 into regs; small tables ----
    unsigned int dw[8];
    {
        const float* W2tmp = (const float*)afb;
        const int col = tid >> 5, d0 = (tid & 31) * 8;
#pragma unroll
        for (int k = 0; k < 8; ++k) {
            int d = d0 + k;
            unsigned int u[2];
#pragma unroll
            for (int h = 0; h < 2; ++h) {
                int idx = d * 2 + h;
                int gg = idx >> 7, j = (idx >> 3) & 15, e = idx & 7;
                int hh = hmap(gg, e);
                float v = (hh >= 0 && j < 12) ? W2tmp[col * 216 + hh * 12 + j] : 0.f;
                u[h] = f16b(v);
            }
            dw[k] = u[0] | (u[1] << 16);
        }
    }
    if (tid < 256) {
        int c2 = tid >> 4, l = tid & 15;
        int gg = l >> 2, q = l & 3;
        unsigned int wu = 0, bu = 0;
        if (q < 3) {
            float mu = smu[c2], rs = srs[c2];
            float w0 = 0.f, b0 = 0.f, w1v = 0.f, b1v = 0.f;
            int h0 = hmap(gg, q * 2), h1_ = hmap(gg, q * 2 + 1);
            if (h0 >= 0) {
                w0 = W1[(size_t)(cols0 + c2) * 18 + h0] * rs;
                b0 = fmaf(-mu, w0, b1[(size_t)(cols0 + c2) * 18 + h0]);
            }
            if (h1_ >= 0) {
                w1v = W1[(size_t)(cols0 + c2) * 18 + h1_] * rs;
                b1v = fmaf(-mu, w1v, b1[(size_t)(cols0 + c2) * 18 + h1_]);
            }
            wu = f16b(w0) | (f16b(w1v) << 16);
            bu = f16b(b0) | (f16b(b1v) << 16);
        }
        w1h[c2][l] = wu;
        b1h[c2][l] = bu;
        b2f[c2][l] = (l < 12) ? b2[(size_t)(cols0 + c2) * 12 + l] : 0.f;
    } else if (tid < 384) {
        int t2 = tid - 256;
        int c2 = t2 >> 3, l = t2 & 7;
        int j0 = 2 * l, j1 = 2 * l + 1;
        float v0 = (j0 < 12) ? W3[(size_t)(cols0 + c2) * 12 + j0] : 0.f;
        float v1 = (j1 < 12) ? W3[(size_t)(cols0 + c2) * 12 + j1] : 0.f;
        w3h[c2][l] = f16b(v0) | (f16b(v1) << 16);
    }
    __syncthreads();

    // ---- S4: write A-frags over W2tmp ----
    {
        const int col = tid >> 5, d0 = (tid & 31) * 8;
#pragma unroll
        for (int k = 0; k < 8; ++k)
            afb[col * 256 + d0 + k] = dw[k];
    }
    __syncthreads();

    // ---- Phase C: dual chained MFMA, 2 cols/wave (sequential), 16 rc/col ----
    const int w = tid >> 6, l = tid & 63;
    const int g = l >> 4, lj = l & 15;
    const h2v z2 = {(_Float16)0.f, (_Float16)0.f};
    const f32x4 zc = {0.f, 0.f, 0.f, 0.f};

#pragma unroll 1
    for (int half = 0; half < 2; ++half) {
        const int cl = w + half * 8;

        union { uint4 u; half8 h; } af;
        af.u = *(const uint4*)&afb[cl * 256 + (g * 16 + lj) * 4];
        union { uint4 u; h2v p[4]; } w1u, b1u;
        w1u.u = *(const uint4*)&w1h[cl][g * 4];
        b1u.u = *(const uint4*)&b1h[cl][g * 4];
        union { uint2 u; half4 h; } a2;
        a2.u = *(const uint2*)&w3h[cl][g * 2];
        f32x4 b2r = *(const f32x4*)&b2f[cl][g * 4];
        float b3v = sb3v[cl];

        float res[4];
        const float* xb = &xt[cl * CS2 + lj];
#pragma unroll
        for (int rc = 0; rc < 16; ++rc) {
            float xsv = xb[rc * 16];                  // conflict-free b32 broadcast-row
            _Float16 xh = (_Float16)xsv;
            h2v x2 = {xh, xh};
            union { h2v p[4]; half8 h; } bf;
            bf.p[0] = __builtin_elementwise_max(x2 * w1u.p[0] + b1u.p[0], z2);
            bf.p[1] = __builtin_elementwise_max(x2 * w1u.p[1] + b1u.p[1], z2);
            bf.p[2] = __builtin_elementwise_max(x2 * w1u.p[2] + b1u.p[2], z2);
            bf.p[3] = z2;

            f32x4 acc = __builtin_amdgcn_mfma_f32_16x16x32_f16(af.h, bf.h, b2r, 0, 0, 0);

            union { fp16x2 c[2]; half4 h; } zf;
            zf.c[0] = __builtin_amdgcn_cvt_pkrtz(fmaxf(acc[0], 0.f), fmaxf(acc[1], 0.f));
            zf.c[1] = __builtin_amdgcn_cvt_pkrtz(fmaxf(acc[2], 0.f), fmaxf(acc[3], 0.f));

            f32x4 acc2 = __builtin_amdgcn_mfma_f32_16x16x16f16(a2.h, zf.h, zc, 0, 0, 0);

            if ((rc >> 2) == g) res[rc & 3] = acc2[0] + b3v;   // rows rc*16+lj
        }
        __syncthreads();                               // all reads of xt[cl] done block-wide
        float* tb = &xt[cl * CS2 + lj];
#pragma unroll
        for (int m = 0; m < 4; ++m)
            tb[(g * 4 + m) * 16] = res[m];             // conflict-free scalar writes
        __syncthreads();
    }

    // ---- store: out[r][c] from xt ----
#pragma unroll
    for (int p = 0; p < 2; ++p) {
        int idx = p * 512 + tid;
        int c4 = idx & 3, r = idx >> 2;
        f32x4 v;
#pragma unroll
        for (int e = 0; e < 4; ++e)
            v[e] = xt[(c4 * 4 + e) * CS2 + r];
        *(f32x4*)(out + (size_t)(rows0 + r) * KLTOT + cols0 + c4 * 4) = v;
    }
}

extern "C" void kernel_launch(void* const* d_in, const int* in_sizes, int n_in,
                              void* d_out, int out_size, void* d_ws, size_t ws_size,
                              hipStream_t stream) {
    const float* x  = (const float*)d_in[0];
    const float* W1 = (const float*)d_in[1];
    const float* b1 = (const float*)d_in[2];
    const float* W2 = (const float*)d_in[3];
    const float* b2 = (const float*)d_in[4];
    const float* W3 = (const float*)d_in[5];
    const float* b3 = (const float*)d_in[6];
    float* out  = (float*)d_out;
    float* part = (float*)d_ws;     // 128 * 2048 * 2 floats = 2 MB

    stats_partial<<<dim3(2, NCHUNK), 256, 0, stream>>>(x, part);
    fused_main   <<<dim3(1024),      512, 0, stream>>>(x, part, W1, b1, W2, b2, W3, b3, out);
}

// Round 15
// 27.061 us; speedup vs baseline: 2.6564x; 1.2879x over previous
//
#include <hip/hip_runtime.h>
#include <hip/hip_fp16.h>

typedef _Float16 half8  __attribute__((ext_vector_type(8)));
typedef _Float16 half4  __attribute__((ext_vector_type(4)));
typedef _Float16 h2v    __attribute__((ext_vector_type(2)));
typedef __fp16   fp16x2 __attribute__((ext_vector_type(2)));
typedef float    f32x4  __attribute__((ext_vector_type(4)));

#define B_N   2048
#define KLTOT 2048
#define P_    2052        // xt col stride (dwords): %32==4 (2-way banks), %4==0 (16B align)

// 5/5/4/4 h-slot packing
__device__ __forceinline__ int hmap(int g, int e) {
    return (g < 2) ? ((e < 5) ? g * 5 + e : -1)
                   : ((e < 4) ? 10 + (g - 2) * 4 + e : -1);
}

__device__ __forceinline__ unsigned int f16b(float f) {
    union { _Float16 h; unsigned short u; } c;
    c.h = (_Float16)f;
    return (unsigned int)c.u;
}

// Single kernel. Block = 4 FULL columns x 2048 batches -> stats are block-local.
// 512 blocks x 512 thr, ~42 KB LDS -> exactly 2 blocks/CU, all co-resident.
__global__ __launch_bounds__(512, 4) void fused_all(
    const float* __restrict__ x,
    const float* __restrict__ W1, const float* __restrict__ b1,
    const float* __restrict__ W2, const float* __restrict__ b2,
    const float* __restrict__ W3, const float* __restrict__ b3,
    float* __restrict__ out)
{
    __shared__ float        xt[4 * P_];          // 32.8 KB  [col][row]
    __shared__ unsigned int afb[1024];           // 4 KB     W2tmp (864 f32) then A-frags
    __shared__ float        wred[8][4][2];
    __shared__ unsigned int w1h[4][16], b1h[4][16], w3h[4][8];
    __shared__ float        b2f[4][16], smu[4], srs[4], sb3v[4];

    const int tid = threadIdx.x;
    const int bid = blockIdx.x;
    // XCD-chunked col swizzle: XCD k owns contiguous 256-col band (2MB x slice < 4MB L2)
    const int xk = bid & 7, jj = bid >> 3;
    const int cols0 = xk * 256 + (jj >> 3) * 32 + (jj & 7) * 4;

    const int w = tid >> 6, l = tid & 63;

    // ---- S1: single x pass: 16B row-slices -> LDS + in-register stats ----
    float s[4] = {0.f,0.f,0.f,0.f}, s2[4] = {0.f,0.f,0.f,0.f};
#pragma unroll
    for (int i = 0; i < 4; ++i) {
        int r = i * 512 + tid;
        f32x4 v = *(const f32x4*)(x + (size_t)r * KLTOT + cols0);
#pragma unroll
        for (int e = 0; e < 4; ++e) {
            s[e] += v[e];
            s2[e] = fmaf(v[e], v[e], s2[e]);
            xt[e * P_ + r] = v[e];
        }
    }
    {   // stage W2 (4 cols x 216 = 864 f32) into afb region
        float* W2tmp = (float*)afb;
        if (tid < 216)
            ((float4*)W2tmp)[tid] = ((const float4*)(W2 + (size_t)cols0 * 216))[tid];
    }
    // prefetch raw W1/b1 (folded after stats)
    float w1r0 = 0.f, w1r1 = 0.f, b1r0 = 0.f, b1r1 = 0.f;
    if (tid < 64) {
        int c2 = tid >> 4, ll = tid & 15, gg = ll >> 2, q = ll & 3;
        if (q < 3) {
            int h0 = hmap(gg, q * 2), h1_ = hmap(gg, q * 2 + 1);
            if (h0 >= 0) {
                w1r0 = W1[(size_t)(cols0 + c2) * 18 + h0];
                b1r0 = b1[(size_t)(cols0 + c2) * 18 + h0];
            }
            if (h1_ >= 0) {
                w1r1 = W1[(size_t)(cols0 + c2) * 18 + h1_];
                b1r1 = b1[(size_t)(cols0 + c2) * 18 + h1_];
            }
        }
    }
    // wave-level stats reduce (8 values x 64 lanes)
#pragma unroll
    for (int e = 0; e < 4; ++e) {
#pragma unroll
        for (int m = 1; m < 64; m <<= 1) {
            s[e]  += __shfl_xor(s[e],  m, 64);
            s2[e] += __shfl_xor(s2[e], m, 64);
        }
    }
    if (l == 0) {
#pragma unroll
        for (int e = 0; e < 4; ++e) { wred[w][e][0] = s[e]; wred[w][e][1] = s2[e]; }
    }
    __syncthreads();

    // ---- S2: stats final (t<4) || W2 frag-pack -> regs || mu-free tables ----
    if (tid < 4) {
        float S = 0.f, S2 = 0.f;
#pragma unroll
        for (int ww = 0; ww < 8; ++ww) { S += wred[ww][tid][0]; S2 += wred[ww][tid][1]; }
        float mu  = S / (float)B_N;
        float var = fmaxf(S2 / (float)B_N - mu * mu, 0.f);
        smu[tid]  = mu;
        srs[tid]  = 1.f / (sqrtf(var) + 1e-8f);
        sb3v[tid] = b3[cols0 + tid];
    }
    unsigned int dw[2];
    {
        const float* W2tmp = (const float*)afb;
#pragma unroll
        for (int i = 0; i < 2; ++i) {
            int idx = i * 512 + tid;           // 1024 frag dwords (4 cols x 256)
            int col = idx >> 8, d = idx & 255;
            unsigned int u[2];
#pragma unroll
            for (int h = 0; h < 2; ++h) {
                int id2 = d * 2 + h;
                int gg = id2 >> 7, jq = (id2 >> 3) & 15, e = id2 & 7;
                int hh = hmap(gg, e);
                float v = (hh >= 0 && jq < 12) ? W2tmp[col * 216 + hh * 12 + jq] : 0.f;
                u[h] = f16b(v);
            }
            dw[i] = u[0] | (u[1] << 16);
        }
    }
    if (tid >= 64 && tid < 128) {
        int t2 = tid - 64, c2 = t2 >> 4, ll = t2 & 15;
        b2f[c2][ll] = (ll < 12) ? b2[(size_t)(cols0 + c2) * 12 + ll] : 0.f;
    } else if (tid >= 128 && tid < 160) {
        int t2 = tid - 128, c2 = t2 >> 3, ll = t2 & 7;
        int j0 = 2 * ll, j1 = 2 * ll + 1;
        float v0 = (j0 < 12) ? W3[(size_t)(cols0 + c2) * 12 + j0] : 0.f;
        float v1 = (j1 < 12) ? W3[(size_t)(cols0 + c2) * 12 + j1] : 0.f;
        w3h[c2][ll] = f16b(v0) | (f16b(v1) << 16);
    }
    __syncthreads();

    // ---- S3: write A-frags || fold W1/b1 with stats ----
#pragma unroll
    for (int i = 0; i < 2; ++i)
        afb[i * 512 + tid] = dw[i];
    if (tid < 64) {
        int c2 = tid >> 4, ll = tid & 15, q = ll & 3;
        unsigned int wu = 0, bu = 0;
        if (q < 3) {
            float mu = smu[c2], rs = srs[c2];
            float w0 = w1r0 * rs, w1v = w1r1 * rs;
            float b0 = fmaf(-mu, w0, b1r0), b1v = fmaf(-mu, w1v, b1r1);
            wu = f16b(w0) | (f16b(w1v) << 16);
            bu = f16b(b0) | (f16b(b1v) << 16);
        }
        w1h[c2][ll] = wu;
        b1h[c2][ll] = bu;
    }
    __syncthreads();

    // ---- Phase C: dual chained MFMA; wave = 1 col x 1024 rows (64 iters) ----
    const int g = l >> 4, lj = l & 15;
    const int cl = w & 3, rb0 = (w >> 2) * 1024;
    const h2v z2 = {(_Float16)0.f, (_Float16)0.f};
    const f32x4 zc = {0.f, 0.f, 0.f, 0.f};

    union { uint4 u; half8 h; } af;
    af.u = *(const uint4*)&afb[cl * 256 + (g * 16 + lj) * 4];
    union { uint4 u; h2v p[4]; } w1u, b1u;
    w1u.u = *(const uint4*)&w1h[cl][g * 4];
    b1u.u = *(const uint4*)&b1h[cl][g * 4];
    union { uint2 u; half4 h; } a2;
    a2.u = *(const uint2*)&w3h[cl][g * 2];
    f32x4 b2r = *(const f32x4*)&b2f[cl][g * 4];
    float b3v = sb3v[cl];

    float res[16];
    const float* xb = &xt[cl * P_ + rb0 + lj];
#pragma unroll
    for (int m16 = 0; m16 < 4; ++m16) {
#pragma unroll
        for (int mi = 0; mi < 16; ++mi) {
            int rc = m16 * 16 + mi;
            float xsv = xb[rc * 16];              // 16-bank broadcast, conflict-free
            _Float16 xh = (_Float16)xsv;
            h2v x2 = {xh, xh};
            union { h2v p[4]; half8 h; } bf;
            bf.p[0] = __builtin_elementwise_max(x2 * w1u.p[0] + b1u.p[0], z2);
            bf.p[1] = __builtin_elementwise_max(x2 * w1u.p[1] + b1u.p[1], z2);
            bf.p[2] = __builtin_elementwise_max(x2 * w1u.p[2] + b1u.p[2], z2);
            bf.p[3] = z2;

            f32x4 acc = __builtin_amdgcn_mfma_f32_16x16x32_f16(af.h, bf.h, b2r, 0, 0, 0);

            union { fp16x2 c[2]; half4 h; } zf;
            zf.c[0] = __builtin_amdgcn_cvt_pkrtz(fmaxf(acc[0], 0.f), fmaxf(acc[1], 0.f));
            zf.c[1] = __builtin_amdgcn_cvt_pkrtz(fmaxf(acc[2], 0.f), fmaxf(acc[3], 0.f));

            f32x4 acc2 = __builtin_amdgcn_mfma_f32_16x16x16f16(a2.h, zf.h, zc, 0, 0, 0);

            if (m16 == g) res[mi] = acc2[0] + b3v;     // rows rb0 + (g*16+mi)*16 + lj
        }
    }
    // overwrite dead x slots (wave-private row range of its own column)
    {
        float* tb = &xt[cl * P_ + rb0 + lj];
#pragma unroll
        for (int mi = 0; mi < 16; ++mi)
            tb[(g * 16 + mi) * 16] = res[mi];
    }
    __syncthreads();

    // ---- store: out[r][cols0..cols0+3] = 16B row-slices (L2-merged) ----
#pragma unroll
    for (int i = 0; i < 4; ++i) {
        int r = i * 512 + tid;
        f32x4 v = { xt[0 * P_ + r], xt[1 * P_ + r], xt[2 * P_ + r], xt[3 * P_ + r] };
        *(f32x4*)(out + (size_t)r * KLTOT + cols0) = v;
    }
}

extern "C" void kernel_launch(void* const* d_in, const int* in_sizes, int n_in,
                              void* d_out, int out_size, void* d_ws, size_t ws_size,
                              hipStream_t stream) {
    const float* x  = (const float*)d_in[0];
    const float* W1 = (const float*)d_in[1];
    const float* b1 = (const float*)d_in[2];
    const float* W2 = (const float*)d_in[3];
    const float* b2 = (const float*)d_in[4];
    const float* W3 = (const float*)d_in[5];
    const float* b3 = (const float*)d_in[6];
    float* out = (float*)d_out;

    fused_all<<<dim3(512), 512, 0, stream>>>(x, W1, b1, W2, b2, W3, b3, out);
}